// Round 10
// baseline (175.074 us; speedup 1.0000x reference)
//
#include <hip/hip_runtime.h>
#include <hip/hip_bf16.h>

// Problem constants
#define N_ROWS 8192
#define F_DIM  512
#define D_DIM  64
#define C_CODES 8192

typedef __attribute__((ext_vector_type(8))) short bf16x8;   // 8 bf16 = 4 VGPRs
typedef __attribute__((ext_vector_type(4))) float f32x4;

__device__ __forceinline__ unsigned short rne_bf16(float x) {
  unsigned u = __float_as_uint(x);
  return (unsigned short)((u + 0x7FFFu + ((u >> 16) & 1u)) >> 16);
}
__device__ __forceinline__ float bf16_to_f(unsigned short u) {
  return __uint_as_float(((unsigned)u) << 16);
}
// split 8 floats into 3 bf16 limbs (h+m+l reproduces x to ~2^-24 rel)
__device__ __forceinline__ void limb3(const float* xs, bf16x8& H, bf16x8& M, bf16x8& L) {
  #pragma unroll
  for (int j = 0; j < 8; ++j) {
    float x = xs[j];
    unsigned short h = rne_bf16(x);
    float r1 = x - bf16_to_f(h);
    unsigned short m = rne_bf16(r1);
    float r2 = r1 - bf16_to_f(m);
    unsigned short lo = rne_bf16(r2);
    H[j] = (short)h; M[j] = (short)m; L[j] = (short)lo;
  }
}

// ---------------------------------------------------------------------------
// P1: fat prep kernel. Blocks 0-15: swizzle W_in; 16-31: swizzle W_out;
// 32-159: normalise codebook emitting fp32 + 3-limb frags. All independent.
__global__ __launch_bounds__(256) void k_prep(
    const float* __restrict__ W_in, const float* __restrict__ W_out,
    const float* __restrict__ cb,
    unsigned short* __restrict__ win_sw, unsigned short* __restrict__ wout_sw,
    float* __restrict__ cn, unsigned short* __restrict__ cn_sw) {
  const int b = blockIdx.x;
  const int tid = threadIdx.x, w = tid >> 6, l = tid & 63;
  const int lo = l & 15, hi = l >> 4;

  if (b < 16) {
    // W_in [512][64] -> frags ((kc*4+cg)*3+m): W_in[kc*32+hi*8+j][cg*16+lo]
    const int task = b * 4 + w;             // 0..63
    const int kc = task >> 2, cg = task & 3;
    float xs[8];
    #pragma unroll
    for (int j = 0; j < 8; ++j)
      xs[j] = W_in[(size_t)(kc * 32 + hi * 8 + j) * D_DIM + cg * 16 + lo];
    bf16x8 H, M, L;
    limb3(xs, H, M, L);
    const int fb = (kc * 4 + cg) * 3;
    unsigned short* d0 = win_sw + (size_t)(fb + 0) * 512 + l * 8;
    unsigned short* d1 = win_sw + (size_t)(fb + 1) * 512 + l * 8;
    unsigned short* d2 = win_sw + (size_t)(fb + 2) * 512 + l * 8;
    #pragma unroll
    for (int j = 0; j < 8; ++j) { d0[j] = (unsigned short)H[j]; d1[j] = (unsigned short)M[j]; d2[j] = (unsigned short)L[j]; }
  } else if (b < 32) {
    // W_out [64][512] -> frags ((cg*2+c)*3+m): W_out[c*32+hi*8+j][cg*16+lo]
    const int task = (b - 16) * 4 + w;      // 0..63
    const int cg = task >> 1, c = task & 1;
    float xs[8];
    #pragma unroll
    for (int j = 0; j < 8; ++j)
      xs[j] = W_out[(size_t)(c * 32 + hi * 8 + j) * F_DIM + cg * 16 + lo];
    bf16x8 H, M, L;
    limb3(xs, H, M, L);
    const int fb = (cg * 2 + c) * 3;
    unsigned short* d0 = wout_sw + (size_t)(fb + 0) * 512 + l * 8;
    unsigned short* d1 = wout_sw + (size_t)(fb + 1) * 512 + l * 8;
    unsigned short* d2 = wout_sw + (size_t)(fb + 2) * 512 + l * 8;
    #pragma unroll
    for (int j = 0; j < 8; ++j) { d0[j] = (unsigned short)H[j]; d1[j] = (unsigned short)M[j]; d2[j] = (unsigned short)L[j]; }
  } else {
    // cn = normalise(codebook), wave = 16 codes, emit fp32 + frags
    const int g = (b - 32) * 4 + w;         // 0..511
    const int code = g * 16 + lo;
    float xs[2][8];
    float s = 0.0f;
    #pragma unroll
    for (int c = 0; c < 2; ++c) {
      const float* sp = cb + (size_t)code * D_DIM + c * 32 + hi * 8;
      float4 a = *(const float4*)sp, bb = *(const float4*)(sp + 4);
      xs[c][0]=a.x; xs[c][1]=a.y; xs[c][2]=a.z; xs[c][3]=a.w;
      xs[c][4]=bb.x; xs[c][5]=bb.y; xs[c][6]=bb.z; xs[c][7]=bb.w;
      #pragma unroll
      for (int j = 0; j < 8; ++j) s += xs[c][j] * xs[c][j];
    }
    s += __shfl_xor(s, 16);
    s += __shfl_xor(s, 32);
    float inv = rsqrtf(s * (1.0f / 64.0f) + 1e-12f);
    #pragma unroll
    for (int c = 0; c < 2; ++c) {
      #pragma unroll
      for (int j = 0; j < 8; ++j) xs[c][j] *= inv;
      float* dp = cn + (size_t)code * D_DIM + c * 32 + hi * 8;
      *(float4*)dp = make_float4(xs[c][0], xs[c][1], xs[c][2], xs[c][3]);
      *(float4*)(dp + 4) = make_float4(xs[c][4], xs[c][5], xs[c][6], xs[c][7]);
      bf16x8 H, M, L;
      limb3(xs[c], H, M, L);
      const int fb = (g * 2 + c) * 3;
      unsigned short* d0 = cn_sw + (size_t)(fb + 0) * 512 + l * 8;
      unsigned short* d1 = cn_sw + (size_t)(fb + 1) * 512 + l * 8;
      unsigned short* d2 = cn_sw + (size_t)(fb + 2) * 512 + l * 8;
      #pragma unroll
      for (int j = 0; j < 8; ++j) { d0[j] = (unsigned short)H[j]; d1[j] = (unsigned short)M[j]; d2[j] = (unsigned short)L[j]; }
    }
  }
}

// ---------------------------------------------------------------------------
// P2: zn = normalise(z @ W_in + b_in), fused swizzle. 512 blocks x 1 wave.
// z prefetch 4-deep (HBM ~900cyc), B ping-pong 1-deep (L2). Also zeroes loss.
__global__ __launch_bounds__(64) void k_zn(
    const float* __restrict__ z, const unsigned short* __restrict__ w_in_sw,
    const float* __restrict__ b_in, float* __restrict__ zn,
    unsigned short* __restrict__ zn_sw, float* __restrict__ loss_zero) {
  __shared__ float t_lds[16 * 65];
  const int l = threadIdx.x;
  const int lo = l & 15, hi = l >> 4;
  const int g = blockIdx.x;                 // 16-row group
  const int r0 = g * 16;
  if (g == 0 && l == 0) loss_zero[0] = 0.0f;
  const bf16x8* Bptr = (const bf16x8*)w_in_sw;
  const float* zbase = z + (size_t)(r0 + lo) * F_DIM + hi * 8;

  f32x4 acc[4];
  #pragma unroll
  for (int cg = 0; cg < 4; ++cg) acc[cg] = (f32x4){0.f, 0.f, 0.f, 0.f};

  bf16x8 Bpp[2][12];
  float4 zq[4][2];
  #pragma unroll
  for (int i = 0; i < 4; ++i) {
    zq[i][0] = *(const float4*)(zbase + i * 32);
    zq[i][1] = *(const float4*)(zbase + i * 32 + 4);
  }
  #pragma unroll
  for (int i = 0; i < 12; ++i) Bpp[0][i] = Bptr[(size_t)i * 64 + l];

  #pragma unroll
  for (int kc = 0; kc < 16; ++kc) {
    float4 na, nb;
    const bool hz = (kc + 4 < 16);
    if (hz) {
      na = *(const float4*)(zbase + (kc + 4) * 32);
      nb = *(const float4*)(zbase + (kc + 4) * 32 + 4);
    }
    if (kc + 1 < 16) {
      #pragma unroll
      for (int i = 0; i < 12; ++i)
        Bpp[(kc + 1) & 1][i] = Bptr[((size_t)(kc + 1) * 12 + i) * 64 + l];
    }
    float xs[8] = {zq[kc & 3][0].x, zq[kc & 3][0].y, zq[kc & 3][0].z, zq[kc & 3][0].w,
                   zq[kc & 3][1].x, zq[kc & 3][1].y, zq[kc & 3][1].z, zq[kc & 3][1].w};
    bf16x8 Ah, Am, Al;
    limb3(xs, Ah, Am, Al);
    #pragma unroll
    for (int cg = 0; cg < 4; ++cg) {
      f32x4 t = acc[cg];
      t = __builtin_amdgcn_mfma_f32_16x16x32_bf16(Ah, Bpp[kc & 1][cg*3+0], t, 0,0,0);
      t = __builtin_amdgcn_mfma_f32_16x16x32_bf16(Ah, Bpp[kc & 1][cg*3+1], t, 0,0,0);
      t = __builtin_amdgcn_mfma_f32_16x16x32_bf16(Am, Bpp[kc & 1][cg*3+0], t, 0,0,0);
      t = __builtin_amdgcn_mfma_f32_16x16x32_bf16(Ah, Bpp[kc & 1][cg*3+2], t, 0,0,0);
      t = __builtin_amdgcn_mfma_f32_16x16x32_bf16(Al, Bpp[kc & 1][cg*3+0], t, 0,0,0);
      t = __builtin_amdgcn_mfma_f32_16x16x32_bf16(Am, Bpp[kc & 1][cg*3+1], t, 0,0,0);
      acc[cg] = t;
    }
    if (hz) { zq[kc & 3][0] = na; zq[kc & 3][1] = nb; }
  }

  // bias + row-normalize (C-layout: col = cg*16+lo, row = hi*4+r)
  #pragma unroll
  for (int r = 0; r < 4; ++r) {
    float v[4], s = 0.0f;
    #pragma unroll
    for (int cg = 0; cg < 4; ++cg) {
      v[cg] = acc[cg][r] + b_in[cg * 16 + lo];
      s += v[cg] * v[cg];
    }
    s += __shfl_xor(s, 1);
    s += __shfl_xor(s, 2);
    s += __shfl_xor(s, 4);
    s += __shfl_xor(s, 8);
    float inv = rsqrtf(s * (1.0f / 64.0f) + 1e-12f);
    #pragma unroll
    for (int cg = 0; cg < 4; ++cg)
      t_lds[(hi * 4 + r) * 65 + cg * 16 + lo] = v[cg] * inv;
  }
  __syncthreads();

  // read back in A-frag order (row = lo, ks = c*32 + hi*8 + j), emit fp32+frags
  #pragma unroll
  for (int c = 0; c < 2; ++c) {
    float xs[8];
    #pragma unroll
    for (int j = 0; j < 8; ++j) xs[j] = t_lds[lo * 65 + c * 32 + hi * 8 + j];
    float* dp = zn + (size_t)(r0 + lo) * D_DIM + c * 32 + hi * 8;
    *(float4*)dp = make_float4(xs[0], xs[1], xs[2], xs[3]);
    *(float4*)(dp + 4) = make_float4(xs[4], xs[5], xs[6], xs[7]);
    bf16x8 H, M, L;
    limb3(xs, H, M, L);
    const int fb = (g * 2 + c) * 3;
    unsigned short* d0 = zn_sw + (size_t)(fb + 0) * 512 + l * 8;
    unsigned short* d1 = zn_sw + (size_t)(fb + 1) * 512 + l * 8;
    unsigned short* d2 = zn_sw + (size_t)(fb + 2) * 512 + l * 8;
    #pragma unroll
    for (int j = 0; j < 8; ++j) { d0[j] = (unsigned short)H[j]; d1[j] = (unsigned short)M[j]; d2[j] = (unsigned short)L[j]; }
  }
}

// ---------------------------------------------------------------------------
// P3: MFMA argmax — R8 structure with B prefetch deepened to 2 (3-buf rotate).
__global__ __launch_bounds__(256, 2) void k_argmax(
    const unsigned short* __restrict__ zn_sw,
    const unsigned short* __restrict__ cn_sw,
    float* __restrict__ pval, int* __restrict__ pidx) {
  const int tid = threadIdx.x;
  const int w = tid >> 6, l = tid & 63;
  const int lo = l & 15, hi = l >> 4;
  const int gA0 = (blockIdx.x * 4 + w) * 2;   // 0..510 (16-row groups)
  const int gB0 = blockIdx.y * 64;            // B group base
  const bf16x8* Ab = (const bf16x8*)zn_sw;
  const bf16x8* Bb = (const bf16x8*)cn_sw;

  bf16x8 A0[2][3], A1[2][3];
  #pragma unroll
  for (int c = 0; c < 2; ++c)
    #pragma unroll
    for (int m = 0; m < 3; ++m) {
      A0[c][m] = Ab[(size_t)((gA0 * 2 + c) * 3 + m) * 64 + l];
      A1[c][m] = Ab[(size_t)(((gA0 + 1) * 2 + c) * 3 + m) * 64 + l];
    }

  float bv[8];
  int bi[8];
  #pragma unroll
  for (int i = 0; i < 8; ++i) { bv[i] = -1e30f; bi[i] = 0; }
  int cand = blockIdx.y * 1024 + lo;

  #define LOADB(dst, gB)                                                     \
    _Pragma("unroll")                                                        \
    for (int c = 0; c < 2; ++c)                                              \
      _Pragma("unroll")                                                      \
      for (int m = 0; m < 3; ++m)                                            \
        dst[c][m] = Bb[(size_t)(((gB) * 2 + c) * 3 + m) * 64 + l];

  #define COMPUTE(B)                                                          \
    {                                                                         \
      f32x4 a0 = {0.f,0.f,0.f,0.f}, a1 = {0.f,0.f,0.f,0.f};                   \
      f32x4 a2 = {0.f,0.f,0.f,0.f}, a3 = {0.f,0.f,0.f,0.f};                   \
      a0 = __builtin_amdgcn_mfma_f32_16x16x32_bf16(A0[0][0], B[0][0], a0, 0,0,0); \
      a1 = __builtin_amdgcn_mfma_f32_16x16x32_bf16(A0[1][0], B[1][0], a1, 0,0,0); \
      a2 = __builtin_amdgcn_mfma_f32_16x16x32_bf16(A1[0][0], B[0][0], a2, 0,0,0); \
      a3 = __builtin_amdgcn_mfma_f32_16x16x32_bf16(A1[1][0], B[1][0], a3, 0,0,0); \
      a0 = __builtin_amdgcn_mfma_f32_16x16x32_bf16(A0[0][0], B[0][1], a0, 0,0,0); \
      a1 = __builtin_amdgcn_mfma_f32_16x16x32_bf16(A0[1][0], B[1][1], a1, 0,0,0); \
      a2 = __builtin_amdgcn_mfma_f32_16x16x32_bf16(A1[0][0], B[0][1], a2, 0,0,0); \
      a3 = __builtin_amdgcn_mfma_f32_16x16x32_bf16(A1[1][0], B[1][1], a3, 0,0,0); \
      a0 = __builtin_amdgcn_mfma_f32_16x16x32_bf16(A0[0][1], B[0][0], a0, 0,0,0); \
      a1 = __builtin_amdgcn_mfma_f32_16x16x32_bf16(A0[1][1], B[1][0], a1, 0,0,0); \
      a2 = __builtin_amdgcn_mfma_f32_16x16x32_bf16(A1[0][1], B[0][0], a2, 0,0,0); \
      a3 = __builtin_amdgcn_mfma_f32_16x16x32_bf16(A1[1][1], B[1][0], a3, 0,0,0); \
      a0 = __builtin_amdgcn_mfma_f32_16x16x32_bf16(A0[0][0], B[0][2], a0, 0,0,0); \
      a1 = __builtin_amdgcn_mfma_f32_16x16x32_bf16(A0[1][0], B[1][2], a1, 0,0,0); \
      a2 = __builtin_amdgcn_mfma_f32_16x16x32_bf16(A1[0][0], B[0][2], a2, 0,0,0); \
      a3 = __builtin_amdgcn_mfma_f32_16x16x32_bf16(A1[1][0], B[1][2], a3, 0,0,0); \
      a0 = __builtin_amdgcn_mfma_f32_16x16x32_bf16(A0[0][2], B[0][0], a0, 0,0,0); \
      a1 = __builtin_amdgcn_mfma_f32_16x16x32_bf16(A0[1][2], B[1][0], a1, 0,0,0); \
      a2 = __builtin_amdgcn_mfma_f32_16x16x32_bf16(A1[0][2], B[0][0], a2, 0,0,0); \
      a3 = __builtin_amdgcn_mfma_f32_16x16x32_bf16(A1[1][2], B[1][0], a3, 0,0,0); \
      a0 = __builtin_amdgcn_mfma_f32_16x16x32_bf16(A0[0][1], B[0][1], a0, 0,0,0); \
      a1 = __builtin_amdgcn_mfma_f32_16x16x32_bf16(A0[1][1], B[1][1], a1, 0,0,0); \
      a2 = __builtin_amdgcn_mfma_f32_16x16x32_bf16(A1[0][1], B[0][1], a2, 0,0,0); \
      a3 = __builtin_amdgcn_mfma_f32_16x16x32_bf16(A1[1][1], B[1][1], a3, 0,0,0); \
      _Pragma("unroll")                                                       \
      for (int r = 0; r < 4; ++r) {                                           \
        float d0 = a0[r] + a1[r];                                             \
        if (d0 > bv[r]) { bv[r] = d0; bi[r] = cand; }                         \
        float d1 = a2[r] + a3[r];                                             \
        if (d1 > bv[4 + r]) { bv[4 + r] = d1; bi[4 + r] = cand; }             \
      }                                                                       \
      cand += 16;                                                             \
    }

  bf16x8 B0v[2][3], B1v[2][3], B2v[2][3];
  LOADB(B0v, gB0);
  LOADB(B1v, gB0 + 1);
  for (int p = 0; p + 3 <= 64; p += 3) {
    LOADB(B2v, gB0 + p + 2);
    COMPUTE(B0v);
    LOADB(B0v, gB0 + p + 3);      // p=60 loads group 63
    COMPUTE(B1v);
    LOADB(B1v, gB0 + p + 4);      // p=60 over-reads group 64 into pad
    COMPUTE(B2v);
  }
  COMPUTE(B0v);                   // pass 63 (group gB0+63)
  #undef LOADB
  #undef COMPUTE

  #pragma unroll
  for (int i = 0; i < 8; ++i) {
    float v = bv[i]; int ix = bi[i];
    #pragma unroll
    for (int m = 1; m < 16; m <<= 1) {
      float ov = __shfl_xor(v, m);
      int oi = __shfl_xor(ix, m);
      if (ov > v || (ov == v && oi < ix)) { v = ov; ix = oi; }
    }
    bv[i] = v; bi[i] = ix;
  }
  if (lo == 0) {
    int off = blockIdx.y * N_ROWS;
    int base0 = gA0 * 16 + hi * 4;
    int base1 = (gA0 + 1) * 16 + hi * 4;
    #pragma unroll
    for (int r = 0; r < 4; ++r) {
      pval[off + base0 + r] = bv[r];     pidx[off + base0 + r] = bi[r];
      pval[off + base1 + r] = bv[4 + r]; pidx[off + base1 + r] = bi[4 + r];
    }
  }
}

// ---------------------------------------------------------------------------
// P4: fused merge + gather + loss (scaled atomic) + out-GEMM. 512 x 1 wave,
// B prefetch 2-deep (3-buffer rotation). No LDS.
__global__ __launch_bounds__(64) void k_out(
    const float* __restrict__ cn, const float* __restrict__ zn,
    const float* __restrict__ pval, const int* __restrict__ pidx,
    const unsigned short* __restrict__ w_out_sw,
    const float* __restrict__ b_out, float* __restrict__ out,
    float* __restrict__ idx_f, float* __restrict__ loss_f) {
  const int l = threadIdx.x;
  const int lo = l & 15, hi = l >> 4;
  const int r0 = blockIdx.x * 16;
  const int row = r0 + lo;

  // merge 8 code-eighth partials (ascending q + strict > => lowest index)
  float v = pval[row];
  int ix = pidx[row];
  #pragma unroll
  for (int q = 1; q < 8; ++q) {
    float vq = pval[q * N_ROWS + row];
    int iq = pidx[q * N_ROWS + row];
    if (vq > v) { v = vq; ix = iq; }
  }
  if (hi == 0) idx_f[row] = (float)ix;

  // gather cn[ix], zn[row] in A-frag order; limb-split; loss partial
  bf16x8 A[2][3];
  float lp = 0.0f;
  #pragma unroll
  for (int c = 0; c < 2; ++c) {
    const float* cp = cn + (size_t)ix * D_DIM + c * 32 + hi * 8;
    const float* zp = zn + (size_t)row * D_DIM + c * 32 + hi * 8;
    float4 c0 = *(const float4*)cp, c1 = *(const float4*)(cp + 4);
    float4 z0 = *(const float4*)zp, z1 = *(const float4*)(zp + 4);
    float xs[8] = {c0.x, c0.y, c0.z, c0.w, c1.x, c1.y, c1.z, c1.w};
    float zs[8] = {z0.x, z0.y, z0.z, z0.w, z1.x, z1.y, z1.z, z1.w};
    limb3(xs, A[c][0], A[c][1], A[c][2]);
    #pragma unroll
    for (int j = 0; j < 8; ++j) { float d = xs[j] - zs[j]; lp += d * d; }
  }
  #pragma unroll
  for (int m = 1; m < 64; m <<= 1) lp += __shfl_xor(lp, m);
  if (l == 0) atomicAdd(loss_f, lp * (1.25f / (float)(N_ROWS * D_DIM)));

  const bf16x8* Bptr = (const bf16x8*)w_out_sw;

  #define LOADW(dst, CG)                                                      \
    _Pragma("unroll")                                                         \
    for (int i = 0; i < 6; ++i)                                               \
      dst[i] = Bptr[((size_t)(CG) * 6 + i) * 64 + l];

  #define OSTEP(BCUR, CG)                                                     \
    {                                                                         \
      f32x4 a0 = {0.f,0.f,0.f,0.f}, a1 = {0.f,0.f,0.f,0.f};                   \
      a0 = __builtin_amdgcn_mfma_f32_16x16x32_bf16(A[0][0], BCUR[0], a0, 0,0,0); \
      a1 = __builtin_amdgcn_mfma_f32_16x16x32_bf16(A[1][0], BCUR[3], a1, 0,0,0); \
      a0 = __builtin_amdgcn_mfma_f32_16x16x32_bf16(A[0][0], BCUR[1], a0, 0,0,0); \
      a1 = __builtin_amdgcn_mfma_f32_16x16x32_bf16(A[1][0], BCUR[4], a1, 0,0,0); \
      a0 = __builtin_amdgcn_mfma_f32_16x16x32_bf16(A[0][1], BCUR[0], a0, 0,0,0); \
      a1 = __builtin_amdgcn_mfma_f32_16x16x32_bf16(A[1][1], BCUR[3], a1, 0,0,0); \
      a0 = __builtin_amdgcn_mfma_f32_16x16x32_bf16(A[0][0], BCUR[2], a0, 0,0,0); \
      a1 = __builtin_amdgcn_mfma_f32_16x16x32_bf16(A[1][0], BCUR[5], a1, 0,0,0); \
      a0 = __builtin_amdgcn_mfma_f32_16x16x32_bf16(A[0][2], BCUR[0], a0, 0,0,0); \
      a1 = __builtin_amdgcn_mfma_f32_16x16x32_bf16(A[1][2], BCUR[3], a1, 0,0,0); \
      a0 = __builtin_amdgcn_mfma_f32_16x16x32_bf16(A[0][1], BCUR[1], a0, 0,0,0); \
      a1 = __builtin_amdgcn_mfma_f32_16x16x32_bf16(A[1][1], BCUR[4], a1, 0,0,0); \
      float bb = b_out[(CG) * 16 + lo];                                       \
      _Pragma("unroll")                                                       \
      for (int r = 0; r < 4; ++r)                                             \
        out[(size_t)(r0 + hi * 4 + r) * F_DIM + (CG) * 16 + lo] =             \
            a0[r] + a1[r] + bb;                                               \
    }

  bf16x8 B0v[6], B1v[6], B2v[6];
  LOADW(B0v, 0);
  LOADW(B1v, 1);
  for (int cg = 0; cg + 3 <= 32; cg += 3) {
    LOADW(B2v, cg + 2);
    OSTEP(B0v, cg);
    LOADW(B0v, cg + 3);
    OSTEP(B1v, cg + 1);
    LOADW(B1v, cg + 4);       // max cg=27 -> loads 31; no over-read
    OSTEP(B2v, cg + 2);
  }
  OSTEP(B0v, 30);
  OSTEP(B1v, 31);
  #undef LOADW
  #undef OSTEP
}

// ---------------------------------------------------------------------------
extern "C" void kernel_launch(void* const* d_in, const int* in_sizes, int n_in,
                              void* d_out, int out_size, void* d_ws, size_t ws_size,
                              hipStream_t stream) {
  const float* z        = (const float*)d_in[0];
  const float* W_in     = (const float*)d_in[1];
  const float* b_in     = (const float*)d_in[2];
  const float* codebook = (const float*)d_in[3];
  const float* W_out    = (const float*)d_in[4];
  const float* b_out    = (const float*)d_in[5];

  float* outp   = (float*)d_out;                      // Output 0: [8192 x 512]
  float* loss_f = outp + (size_t)N_ROWS * F_DIM;      // Output 1
  float* idx_f  = loss_f + 1;                         // Output 2

  // workspace layout (float units)
  float* wsf = (float*)d_ws;
  float* zn_ws = wsf;                                         // [0, 524288)
  float* cn_ws = wsf + 524288;                                // [524288, 1048576)
  unsigned short* zn_sw = (unsigned short*)(wsf + 1048576);   // 786432 f
  unsigned short* cn_sw = (unsigned short*)(wsf + 1835008);   // 786432 f, ends 2621440
  // 16 KB pad @ [2621440, 2625536) for argmax B over-read
  unsigned short* win_sw  = (unsigned short*)(wsf + 2625536); // 49152 f
  unsigned short* wout_sw = (unsigned short*)(wsf + 2674688); // 49152 f
  float* pval_ws = wsf + 2723840;                             // 65536 f (8 x 8192)
  int*   pidx_ws = (int*)(wsf + 2789376);                     // 65536 ints
  // total 2854912 floats ~ 11.4 MB

  hipLaunchKernelGGL(k_prep, dim3(160), dim3(256), 0, stream,
                     W_in, W_out, codebook, win_sw, wout_sw, cn_ws, cn_sw);
  hipLaunchKernelGGL(k_zn, dim3(512), dim3(64), 0, stream,
                     z, win_sw, b_in, zn_ws, zn_sw, loss_f);
  hipLaunchKernelGGL(k_argmax, dim3(64, 8), dim3(256), 0, stream,
                     zn_sw, cn_sw, pval_ws, pidx_ws);
  hipLaunchKernelGGL(k_out, dim3(512), dim3(64), 0, stream,
                     cn_ws, zn_ws, pval_ws, pidx_ws, wout_sw, b_out,
                     outp, idx_f, loss_f);
}

// Round 11
// 155.169 us; speedup vs baseline: 1.1283x; 1.1283x over previous
//
#include <hip/hip_runtime.h>
#include <hip/hip_bf16.h>

// Problem constants
#define N_ROWS 8192
#define F_DIM  512
#define D_DIM  64
#define C_CODES 8192

typedef __attribute__((ext_vector_type(8))) short bf16x8;   // 8 bf16 = 4 VGPRs
typedef __attribute__((ext_vector_type(4))) float f32x4;

__device__ __forceinline__ unsigned short rne_bf16(float x) {
  unsigned u = __float_as_uint(x);
  return (unsigned short)((u + 0x7FFFu + ((u >> 16) & 1u)) >> 16);
}
__device__ __forceinline__ float bf16_to_f(unsigned short u) {
  return __uint_as_float(((unsigned)u) << 16);
}
// split 8 floats into 3 bf16 limbs (h+m+l reproduces x to ~2^-24 rel)
__device__ __forceinline__ void limb3(const float* xs, bf16x8& H, bf16x8& M, bf16x8& L) {
  #pragma unroll
  for (int j = 0; j < 8; ++j) {
    float x = xs[j];
    unsigned short h = rne_bf16(x);
    float r1 = x - bf16_to_f(h);
    unsigned short m = rne_bf16(r1);
    float r2 = r1 - bf16_to_f(m);
    unsigned short lo = rne_bf16(r2);
    H[j] = (short)h; M[j] = (short)m; L[j] = (short)lo;
  }
}

// ---------------------------------------------------------------------------
// P1: fat prep kernel (kept from R10). Blocks 0-15: swizzle W_in; 16-31:
// swizzle W_out; 32-159: normalise codebook emitting fp32 + 3-limb frags.
__global__ __launch_bounds__(256) void k_prep(
    const float* __restrict__ W_in, const float* __restrict__ W_out,
    const float* __restrict__ cb,
    unsigned short* __restrict__ win_sw, unsigned short* __restrict__ wout_sw,
    float* __restrict__ cn, unsigned short* __restrict__ cn_sw) {
  const int b = blockIdx.x;
  const int tid = threadIdx.x, w = tid >> 6, l = tid & 63;
  const int lo = l & 15, hi = l >> 4;

  if (b < 16) {
    const int task = b * 4 + w;             // 0..63
    const int kc = task >> 2, cg = task & 3;
    float xs[8];
    #pragma unroll
    for (int j = 0; j < 8; ++j)
      xs[j] = W_in[(size_t)(kc * 32 + hi * 8 + j) * D_DIM + cg * 16 + lo];
    bf16x8 H, M, L;
    limb3(xs, H, M, L);
    const int fb = (kc * 4 + cg) * 3;
    unsigned short* d0 = win_sw + (size_t)(fb + 0) * 512 + l * 8;
    unsigned short* d1 = win_sw + (size_t)(fb + 1) * 512 + l * 8;
    unsigned short* d2 = win_sw + (size_t)(fb + 2) * 512 + l * 8;
    #pragma unroll
    for (int j = 0; j < 8; ++j) { d0[j] = (unsigned short)H[j]; d1[j] = (unsigned short)M[j]; d2[j] = (unsigned short)L[j]; }
  } else if (b < 32) {
    const int task = (b - 16) * 4 + w;      // 0..63
    const int cg = task >> 1, c = task & 1;
    float xs[8];
    #pragma unroll
    for (int j = 0; j < 8; ++j)
      xs[j] = W_out[(size_t)(c * 32 + hi * 8 + j) * F_DIM + cg * 16 + lo];
    bf16x8 H, M, L;
    limb3(xs, H, M, L);
    const int fb = (cg * 2 + c) * 3;
    unsigned short* d0 = wout_sw + (size_t)(fb + 0) * 512 + l * 8;
    unsigned short* d1 = wout_sw + (size_t)(fb + 1) * 512 + l * 8;
    unsigned short* d2 = wout_sw + (size_t)(fb + 2) * 512 + l * 8;
    #pragma unroll
    for (int j = 0; j < 8; ++j) { d0[j] = (unsigned short)H[j]; d1[j] = (unsigned short)M[j]; d2[j] = (unsigned short)L[j]; }
  } else {
    const int g = (b - 32) * 4 + w;         // 0..511
    const int code = g * 16 + lo;
    float xs[2][8];
    float s = 0.0f;
    #pragma unroll
    for (int c = 0; c < 2; ++c) {
      const float* sp = cb + (size_t)code * D_DIM + c * 32 + hi * 8;
      float4 a = *(const float4*)sp, bb = *(const float4*)(sp + 4);
      xs[c][0]=a.x; xs[c][1]=a.y; xs[c][2]=a.z; xs[c][3]=a.w;
      xs[c][4]=bb.x; xs[c][5]=bb.y; xs[c][6]=bb.z; xs[c][7]=bb.w;
      #pragma unroll
      for (int j = 0; j < 8; ++j) s += xs[c][j] * xs[c][j];
    }
    s += __shfl_xor(s, 16);
    s += __shfl_xor(s, 32);
    float inv = rsqrtf(s * (1.0f / 64.0f) + 1e-12f);
    #pragma unroll
    for (int c = 0; c < 2; ++c) {
      #pragma unroll
      for (int j = 0; j < 8; ++j) xs[c][j] *= inv;
      float* dp = cn + (size_t)code * D_DIM + c * 32 + hi * 8;
      *(float4*)dp = make_float4(xs[c][0], xs[c][1], xs[c][2], xs[c][3]);
      *(float4*)(dp + 4) = make_float4(xs[c][4], xs[c][5], xs[c][6], xs[c][7]);
      bf16x8 H, M, L;
      limb3(xs[c], H, M, L);
      const int fb = (g * 2 + c) * 3;
      unsigned short* d0 = cn_sw + (size_t)(fb + 0) * 512 + l * 8;
      unsigned short* d1 = cn_sw + (size_t)(fb + 1) * 512 + l * 8;
      unsigned short* d2 = cn_sw + (size_t)(fb + 2) * 512 + l * 8;
      #pragma unroll
      for (int j = 0; j < 8; ++j) { d0[j] = (unsigned short)H[j]; d1[j] = (unsigned short)M[j]; d2[j] = (unsigned short)L[j]; }
    }
  }
}

// ---------------------------------------------------------------------------
// P2: zn = normalise(z @ W_in + b_in), fused swizzle — R9-proven body
// (1-deep ping-pong), plus loss zeroing. 512 blocks x 1 wave.
__global__ __launch_bounds__(64) void k_zn(
    const float* __restrict__ z, const unsigned short* __restrict__ w_in_sw,
    const float* __restrict__ b_in, float* __restrict__ zn,
    unsigned short* __restrict__ zn_sw, float* __restrict__ loss_zero) {
  __shared__ float t_lds[16 * 65];
  const int l = threadIdx.x;
  const int lo = l & 15, hi = l >> 4;
  const int g = blockIdx.x;                 // 16-row group
  const int r0 = g * 16;
  if (g == 0 && l == 0) loss_zero[0] = 0.0f;
  const bf16x8* Bptr = (const bf16x8*)w_in_sw;
  const float* zbase = z + (size_t)(r0 + lo) * F_DIM + hi * 8;

  f32x4 acc[4];
  #pragma unroll
  for (int cg = 0; cg < 4; ++cg) acc[cg] = (f32x4){0.f, 0.f, 0.f, 0.f};

  bf16x8 Bu[12], Bv[12];
  #pragma unroll
  for (int i = 0; i < 12; ++i) Bu[i] = Bptr[(size_t)i * 64 + l];
  float4 za = *(const float4*)zbase;
  float4 zb = *(const float4*)(zbase + 4);

  #define ZSTEP(BCUR, BNXT, KC)                                               \
    {                                                                         \
      int kn = ((KC) < 15) ? (KC) + 1 : 15;                                   \
      float4 na = *(const float4*)(zbase + kn * 32);                          \
      float4 nb = *(const float4*)(zbase + kn * 32 + 4);                      \
      _Pragma("unroll")                                                       \
      for (int i = 0; i < 12; ++i)                                            \
        BNXT[i] = Bptr[((size_t)kn * 12 + i) * 64 + l];                       \
      float xs[8] = {za.x, za.y, za.z, za.w, zb.x, zb.y, zb.z, zb.w};         \
      bf16x8 Ah, Am, Al;                                                      \
      limb3(xs, Ah, Am, Al);                                                  \
      _Pragma("unroll")                                                       \
      for (int cg = 0; cg < 4; ++cg) {                                        \
        f32x4 t = acc[cg];                                                    \
        t = __builtin_amdgcn_mfma_f32_16x16x32_bf16(Ah, BCUR[cg*3+0], t, 0,0,0); \
        t = __builtin_amdgcn_mfma_f32_16x16x32_bf16(Ah, BCUR[cg*3+1], t, 0,0,0); \
        t = __builtin_amdgcn_mfma_f32_16x16x32_bf16(Am, BCUR[cg*3+0], t, 0,0,0); \
        t = __builtin_amdgcn_mfma_f32_16x16x32_bf16(Ah, BCUR[cg*3+2], t, 0,0,0); \
        t = __builtin_amdgcn_mfma_f32_16x16x32_bf16(Al, BCUR[cg*3+0], t, 0,0,0); \
        t = __builtin_amdgcn_mfma_f32_16x16x32_bf16(Am, BCUR[cg*3+1], t, 0,0,0); \
        acc[cg] = t;                                                          \
      }                                                                       \
      za = na; zb = nb;                                                       \
    }

  for (int kc = 0; kc < 16; kc += 2) {
    ZSTEP(Bu, Bv, kc)
    ZSTEP(Bv, Bu, kc + 1)
  }
  #undef ZSTEP

  // bias + row-normalize (C-layout: col = cg*16+lo, row = hi*4+r)
  #pragma unroll
  for (int r = 0; r < 4; ++r) {
    float v[4], s = 0.0f;
    #pragma unroll
    for (int cg = 0; cg < 4; ++cg) {
      v[cg] = acc[cg][r] + b_in[cg * 16 + lo];
      s += v[cg] * v[cg];
    }
    s += __shfl_xor(s, 1);
    s += __shfl_xor(s, 2);
    s += __shfl_xor(s, 4);
    s += __shfl_xor(s, 8);
    float inv = rsqrtf(s * (1.0f / 64.0f) + 1e-12f);
    #pragma unroll
    for (int cg = 0; cg < 4; ++cg)
      t_lds[(hi * 4 + r) * 65 + cg * 16 + lo] = v[cg] * inv;
  }
  __syncthreads();

  // read back in A-frag order (row = lo, ks = c*32 + hi*8 + j), emit fp32+frags
  #pragma unroll
  for (int c = 0; c < 2; ++c) {
    float xs[8];
    #pragma unroll
    for (int j = 0; j < 8; ++j) xs[j] = t_lds[lo * 65 + c * 32 + hi * 8 + j];
    float* dp = zn + (size_t)(r0 + lo) * D_DIM + c * 32 + hi * 8;
    *(float4*)dp = make_float4(xs[0], xs[1], xs[2], xs[3]);
    *(float4*)(dp + 4) = make_float4(xs[4], xs[5], xs[6], xs[7]);
    bf16x8 H, M, L;
    limb3(xs, H, M, L);
    const int fb = (g * 2 + c) * 3;
    unsigned short* d0 = zn_sw + (size_t)(fb + 0) * 512 + l * 8;
    unsigned short* d1 = zn_sw + (size_t)(fb + 1) * 512 + l * 8;
    unsigned short* d2 = zn_sw + (size_t)(fb + 2) * 512 + l * 8;
    #pragma unroll
    for (int j = 0; j < 8; ++j) { d0[j] = (unsigned short)H[j]; d1[j] = (unsigned short)M[j]; d2[j] = (unsigned short)L[j]; }
  }
}

// ---------------------------------------------------------------------------
// P3: MFMA argmax — exact R8/R9-proven body (1-deep ping-pong, 47.2 us).
__global__ __launch_bounds__(256, 2) void k_argmax(
    const unsigned short* __restrict__ zn_sw,
    const unsigned short* __restrict__ cn_sw,
    float* __restrict__ pval, int* __restrict__ pidx) {
  const int tid = threadIdx.x;
  const int w = tid >> 6, l = tid & 63;
  const int lo = l & 15, hi = l >> 4;
  const int gA0 = (blockIdx.x * 4 + w) * 2;   // 0..510 (16-row groups)
  const int gB0 = blockIdx.y * 64;            // B group base
  const bf16x8* Ab = (const bf16x8*)zn_sw;
  const bf16x8* Bb = (const bf16x8*)cn_sw;

  bf16x8 A0[2][3], A1[2][3];
  #pragma unroll
  for (int c = 0; c < 2; ++c)
    #pragma unroll
    for (int m = 0; m < 3; ++m) {
      A0[c][m] = Ab[(size_t)((gA0 * 2 + c) * 3 + m) * 64 + l];
      A1[c][m] = Ab[(size_t)(((gA0 + 1) * 2 + c) * 3 + m) * 64 + l];
    }

  bf16x8 Bu[2][3], Bv[2][3];
  #pragma unroll
  for (int c = 0; c < 2; ++c)
    #pragma unroll
    for (int m = 0; m < 3; ++m)
      Bu[c][m] = Bb[(size_t)((gB0 * 2 + c) * 3 + m) * 64 + l];

  float bv[8];
  int bi[8];
  #pragma unroll
  for (int i = 0; i < 8; ++i) { bv[i] = -1e30f; bi[i] = 0; }
  int cand = blockIdx.y * 1024 + lo;

  #define LOADB(dst, gB)                                                     \
    _Pragma("unroll")                                                        \
    for (int c = 0; c < 2; ++c)                                              \
      _Pragma("unroll")                                                      \
      for (int m = 0; m < 3; ++m)                                            \
        dst[c][m] = Bb[(size_t)(((gB) * 2 + c) * 3 + m) * 64 + l];

  #define COMPUTE(B)                                                          \
    {                                                                         \
      f32x4 a0 = {0.f,0.f,0.f,0.f}, a1 = {0.f,0.f,0.f,0.f};                   \
      f32x4 a2 = {0.f,0.f,0.f,0.f}, a3 = {0.f,0.f,0.f,0.f};                   \
      a0 = __builtin_amdgcn_mfma_f32_16x16x32_bf16(A0[0][0], B[0][0], a0, 0,0,0); \
      a1 = __builtin_amdgcn_mfma_f32_16x16x32_bf16(A0[1][0], B[1][0], a1, 0,0,0); \
      a2 = __builtin_amdgcn_mfma_f32_16x16x32_bf16(A1[0][0], B[0][0], a2, 0,0,0); \
      a3 = __builtin_amdgcn_mfma_f32_16x16x32_bf16(A1[1][0], B[1][0], a3, 0,0,0); \
      a0 = __builtin_amdgcn_mfma_f32_16x16x32_bf16(A0[0][0], B[0][1], a0, 0,0,0); \
      a1 = __builtin_amdgcn_mfma_f32_16x16x32_bf16(A0[1][0], B[1][1], a1, 0,0,0); \
      a2 = __builtin_amdgcn_mfma_f32_16x16x32_bf16(A1[0][0], B[0][1], a2, 0,0,0); \
      a3 = __builtin_amdgcn_mfma_f32_16x16x32_bf16(A1[1][0], B[1][1], a3, 0,0,0); \
      a0 = __builtin_amdgcn_mfma_f32_16x16x32_bf16(A0[0][1], B[0][0], a0, 0,0,0); \
      a1 = __builtin_amdgcn_mfma_f32_16x16x32_bf16(A0[1][1], B[1][0], a1, 0,0,0); \
      a2 = __builtin_amdgcn_mfma_f32_16x16x32_bf16(A1[0][1], B[0][0], a2, 0,0,0); \
      a3 = __builtin_amdgcn_mfma_f32_16x16x32_bf16(A1[1][1], B[1][0], a3, 0,0,0); \
      a0 = __builtin_amdgcn_mfma_f32_16x16x32_bf16(A0[0][0], B[0][2], a0, 0,0,0); \
      a1 = __builtin_amdgcn_mfma_f32_16x16x32_bf16(A0[1][0], B[1][2], a1, 0,0,0); \
      a2 = __builtin_amdgcn_mfma_f32_16x16x32_bf16(A1[0][0], B[0][2], a2, 0,0,0); \
      a3 = __builtin_amdgcn_mfma_f32_16x16x32_bf16(A1[1][0], B[1][2], a3, 0,0,0); \
      a0 = __builtin_amdgcn_mfma_f32_16x16x32_bf16(A0[0][2], B[0][0], a0, 0,0,0); \
      a1 = __builtin_amdgcn_mfma_f32_16x16x32_bf16(A0[1][2], B[1][0], a1, 0,0,0); \
      a2 = __builtin_amdgcn_mfma_f32_16x16x32_bf16(A1[0][2], B[0][0], a2, 0,0,0); \
      a3 = __builtin_amdgcn_mfma_f32_16x16x32_bf16(A1[1][2], B[1][0], a3, 0,0,0); \
      a0 = __builtin_amdgcn_mfma_f32_16x16x32_bf16(A0[0][1], B[0][1], a0, 0,0,0); \
      a1 = __builtin_amdgcn_mfma_f32_16x16x32_bf16(A0[1][1], B[1][1], a1, 0,0,0); \
      a2 = __builtin_amdgcn_mfma_f32_16x16x32_bf16(A1[0][1], B[0][1], a2, 0,0,0); \
      a3 = __builtin_amdgcn_mfma_f32_16x16x32_bf16(A1[1][1], B[1][1], a3, 0,0,0); \
      _Pragma("unroll")                                                       \
      for (int r = 0; r < 4; ++r) {                                           \
        float d0 = a0[r] + a1[r];                                             \
        if (d0 > bv[r]) { bv[r] = d0; bi[r] = cand; }                         \
        float d1 = a2[r] + a3[r];                                             \
        if (d1 > bv[4 + r]) { bv[4 + r] = d1; bi[4 + r] = cand; }             \
      }                                                                       \
      cand += 16;                                                             \
    }

  for (int p = 0; p < 64; p += 2) {
    LOADB(Bv, gB0 + p + 1);
    COMPUTE(Bu);
    LOADB(Bu, gB0 + p + 2);   // last iter over-reads one group into pad
    COMPUTE(Bv);
  }
  #undef LOADB
  #undef COMPUTE

  #pragma unroll
  for (int i = 0; i < 8; ++i) {
    float v = bv[i]; int ix = bi[i];
    #pragma unroll
    for (int m = 1; m < 16; m <<= 1) {
      float ov = __shfl_xor(v, m);
      int oi = __shfl_xor(ix, m);
      if (ov > v || (ov == v && oi < ix)) { v = ov; ix = oi; }
    }
    bv[i] = v; bi[i] = ix;
  }
  if (lo == 0) {
    int off = blockIdx.y * N_ROWS;
    int base0 = gA0 * 16 + hi * 4;
    int base1 = (gA0 + 1) * 16 + hi * 4;
    #pragma unroll
    for (int r = 0; r < 4; ++r) {
      pval[off + base0 + r] = bv[r];     pidx[off + base0 + r] = bi[r];
      pval[off + base1 + r] = bv[4 + r]; pidx[off + base1 + r] = bi[4 + r];
    }
  }
}

// ---------------------------------------------------------------------------
// P4: fused merge + gather + loss (scaled atomic) + out-GEMM — R9-proven
// ping-pong body. 512 x 1 wave. No LDS.
__global__ __launch_bounds__(64) void k_out(
    const float* __restrict__ cn, const float* __restrict__ zn,
    const float* __restrict__ pval, const int* __restrict__ pidx,
    const unsigned short* __restrict__ w_out_sw,
    const float* __restrict__ b_out, float* __restrict__ out,
    float* __restrict__ idx_f, float* __restrict__ loss_f) {
  const int l = threadIdx.x;
  const int lo = l & 15, hi = l >> 4;
  const int r0 = blockIdx.x * 16;
  const int row = r0 + lo;

  // merge 8 code-eighth partials (ascending q + strict > => lowest index)
  float v = pval[row];
  int ix = pidx[row];
  #pragma unroll
  for (int q = 1; q < 8; ++q) {
    float vq = pval[q * N_ROWS + row];
    int iq = pidx[q * N_ROWS + row];
    if (vq > v) { v = vq; ix = iq; }
  }
  if (hi == 0) idx_f[row] = (float)ix;

  // gather cn[ix], zn[row] in A-frag order; limb-split; loss partial
  bf16x8 A[2][3];
  float lp = 0.0f;
  #pragma unroll
  for (int c = 0; c < 2; ++c) {
    const float* cp = cn + (size_t)ix * D_DIM + c * 32 + hi * 8;
    const float* zp = zn + (size_t)row * D_DIM + c * 32 + hi * 8;
    float4 c0 = *(const float4*)cp, c1 = *(const float4*)(cp + 4);
    float4 z0 = *(const float4*)zp, z1 = *(const float4*)(zp + 4);
    float xs[8] = {c0.x, c0.y, c0.z, c0.w, c1.x, c1.y, c1.z, c1.w};
    float zs[8] = {z0.x, z0.y, z0.z, z0.w, z1.x, z1.y, z1.z, z1.w};
    limb3(xs, A[c][0], A[c][1], A[c][2]);
    #pragma unroll
    for (int j = 0; j < 8; ++j) { float d = xs[j] - zs[j]; lp += d * d; }
  }
  #pragma unroll
  for (int m = 1; m < 64; m <<= 1) lp += __shfl_xor(lp, m);
  if (l == 0) atomicAdd(loss_f, lp * (1.25f / (float)(N_ROWS * D_DIM)));

  const bf16x8* Bptr = (const bf16x8*)w_out_sw;
  bf16x8 Bu[6], Bv[6];
  #pragma unroll
  for (int i = 0; i < 6; ++i) Bu[i] = Bptr[(size_t)i * 64 + l];

  #define OSTEP(BCUR, BNXT, CG)                                               \
    {                                                                         \
      _Pragma("unroll")                                                       \
      for (int i = 0; i < 6; ++i)                                             \
        BNXT[i] = Bptr[((size_t)((CG) + 1) * 6 + i) * 64 + l];                \
      f32x4 a0 = {0.f,0.f,0.f,0.f}, a1 = {0.f,0.f,0.f,0.f};                   \
      a0 = __builtin_amdgcn_mfma_f32_16x16x32_bf16(A[0][0], BCUR[0], a0, 0,0,0); \
      a1 = __builtin_amdgcn_mfma_f32_16x16x32_bf16(A[1][0], BCUR[3], a1, 0,0,0); \
      a0 = __builtin_amdgcn_mfma_f32_16x16x32_bf16(A[0][0], BCUR[1], a0, 0,0,0); \
      a1 = __builtin_amdgcn_mfma_f32_16x16x32_bf16(A[1][0], BCUR[4], a1, 0,0,0); \
      a0 = __builtin_amdgcn_mfma_f32_16x16x32_bf16(A[0][1], BCUR[0], a0, 0,0,0); \
      a1 = __builtin_amdgcn_mfma_f32_16x16x32_bf16(A[1][1], BCUR[3], a1, 0,0,0); \
      a0 = __builtin_amdgcn_mfma_f32_16x16x32_bf16(A[0][0], BCUR[2], a0, 0,0,0); \
      a1 = __builtin_amdgcn_mfma_f32_16x16x32_bf16(A[1][0], BCUR[5], a1, 0,0,0); \
      a0 = __builtin_amdgcn_mfma_f32_16x16x32_bf16(A[0][2], BCUR[0], a0, 0,0,0); \
      a1 = __builtin_amdgcn_mfma_f32_16x16x32_bf16(A[1][2], BCUR[3], a1, 0,0,0); \
      a0 = __builtin_amdgcn_mfma_f32_16x16x32_bf16(A[0][1], BCUR[1], a0, 0,0,0); \
      a1 = __builtin_amdgcn_mfma_f32_16x16x32_bf16(A[1][1], BCUR[4], a1, 0,0,0); \
      float bb = b_out[(CG) * 16 + lo];                                       \
      _Pragma("unroll")                                                       \
      for (int r = 0; r < 4; ++r)                                             \
        out[(size_t)(r0 + hi * 4 + r) * F_DIM + (CG) * 16 + lo] =             \
            a0[r] + a1[r] + bb;                                               \
    }

  for (int cg = 0; cg < 32; cg += 2) {
    OSTEP(Bu, Bv, cg)          // cg=31's prefetch over-reads 6KB past wout_sw
    OSTEP(Bv, Bu, cg + 1)      // (lands in pval scratch - harmless reads)
  }
  #undef OSTEP
}

// ---------------------------------------------------------------------------
extern "C" void kernel_launch(void* const* d_in, const int* in_sizes, int n_in,
                              void* d_out, int out_size, void* d_ws, size_t ws_size,
                              hipStream_t stream) {
  const float* z        = (const float*)d_in[0];
  const float* W_in     = (const float*)d_in[1];
  const float* b_in     = (const float*)d_in[2];
  const float* codebook = (const float*)d_in[3];
  const float* W_out    = (const float*)d_in[4];
  const float* b_out    = (const float*)d_in[5];

  float* outp   = (float*)d_out;                      // Output 0: [8192 x 512]
  float* loss_f = outp + (size_t)N_ROWS * F_DIM;      // Output 1
  float* idx_f  = loss_f + 1;                         // Output 2

  // workspace layout (float units)
  float* wsf = (float*)d_ws;
  float* zn_ws = wsf;                                         // [0, 524288)
  float* cn_ws = wsf + 524288;                                // [524288, 1048576)
  unsigned short* zn_sw = (unsigned short*)(wsf + 1048576);   // 786432 f
  unsigned short* cn_sw = (unsigned short*)(wsf + 1835008);   // 786432 f, ends 2621440
  // 16 KB pad @ [2621440, 2625536) for argmax B over-read
  unsigned short* win_sw  = (unsigned short*)(wsf + 2625536); // 49152 f
  unsigned short* wout_sw = (unsigned short*)(wsf + 2674688); // 49152 f
  float* pval_ws = wsf + 2723840;                             // 65536 f (8 x 8192)
  int*   pidx_ws = (int*)(wsf + 2789376);                     // 65536 ints
  // total 2854912 floats ~ 11.4 MB

  hipLaunchKernelGGL(k_prep, dim3(160), dim3(256), 0, stream,
                     W_in, W_out, codebook, win_sw, wout_sw, cn_ws, cn_sw);
  hipLaunchKernelGGL(k_zn, dim3(512), dim3(64), 0, stream,
                     z, win_sw, b_in, zn_ws, zn_sw, loss_f);
  hipLaunchKernelGGL(k_argmax, dim3(64, 8), dim3(256), 0, stream,
                     zn_sw, cn_sw, pval_ws, pidx_ws);
  hipLaunchKernelGGL(k_out, dim3(512), dim3(64), 0, stream,
                     cn_ws, zn_ws, pval_ws, pidx_ws, wout_sw, b_out,
                     outp, idx_f, loss_f);
}